// Round 2
// baseline (1554.410 us; speedup 1.0000x reference)
//
#include <hip/hip_runtime.h>

#define BATCH 16384
#define CH 512
#define EPSBN 1e-5f

typedef __attribute__((ext_vector_type(8))) short short8;
typedef __attribute__((ext_vector_type(4))) float f32x4;
typedef __attribute__((ext_vector_type(4))) unsigned short ushort4v;

static __device__ __forceinline__ unsigned short f2b(float f){
  union { float f; unsigned u; } v; v.f = f;
  unsigned r = v.u + 0x7fffu + ((v.u >> 16) & 1u);
  return (unsigned short)(r >> 16);
}
static __device__ __forceinline__ float b2f(unsigned short u){
  union { unsigned u; float f; } v; v.u = ((unsigned)u) << 16; return v.f;
}

// ---------------- sentinel (ws too small) ----------------
__global__ void k_sentinel(float* out){ out[0] = 1.0e6f; }

// ---------------- index / wscale ----------------
__global__ void k_index(const float* __restrict__ ap, const float* __restrict__ gum,
                        int* __restrict__ idx, float* __restrict__ wsc){
  int e = threadIdx.x;
  if (e >= 21) return;
  const float* a = ap + e*9;
  const float* g = gum + e*9;
  float m = a[0];
  for (int o=1;o<9;o++) m = fmaxf(m, a[o]);
  float s = 0.f;
  for (int o=0;o<9;o++) s += expf(a[o]-m);
  float lse = m + logf(s);
  float lg[9]; float lm = -1e30f;
  for (int o=0;o<9;o++){ lg[o] = (a[o]-lse+g[o]) / 10.0f; lm = fmaxf(lm, lg[o]); }
  float ss = 0.f;
  for (int o=0;o<9;o++) ss += expf(lg[o]-lm);
  int bi = 0; float bp = -1.f;
  for (int o=0;o<9;o++){
    float p = expf(lg[o]-lm)/ss;
    if (p > bp){ bp = p; bi = o; }
  }
  idx[e] = bi;
  wsc[e] = (1.0f - bp) + bp;   // == hardwts[e, index[e]] numerically
}

// ---------------- fp32 -> bf16 (vector4) ----------------
__global__ void k_f2b4(const float* __restrict__ in, unsigned short* __restrict__ outp, long n4){
  long i = (long)blockIdx.x*blockDim.x + threadIdx.x;
  if (i >= n4) return;
  const float4 v = ((const float4*)in)[i];
  ushort4v o;
  o[0] = f2b(v.x); o[1] = f2b(v.y); o[2] = f2b(v.z); o[3] = f2b(v.w);
  ((ushort4v*)outp)[i] = o;
}

// ---------------- selected-weight convert ----------------
__global__ void k_wconv(const int* __restrict__ idxp, int eidx, int isA,
                        const float* __restrict__ dw, const float* __restrict__ pw,
                        const float* __restrict__ gw, int cin,
                        unsigned short* __restrict__ Wb){
  int id = idxp[eidx];
  const float* src; long n;
  if (id >= 2 && id <= 4){ n = (long)CH*cin; src = dw + (long)(id-2)*n; }
  else if (id <= 1 && isA){ n = (long)CH*cin; src = pw + (long)id*n; }
  else if (id >= 5 && id <= 7){ n = (long)CH*(cin/4); src = gw + (long)(id-5)*n; }
  else return;
  long stride = (long)gridDim.x*blockDim.x;
  for (long i = (long)blockIdx.x*blockDim.x + threadIdx.x; i < n; i += stride)
    Wb[i] = f2b(src[i]);
}

// ---------------- per-edge GEMM (bf16 MFMA 16x16x32) ----------------
// dense/gdense: acc += we * act(h@W^T + b);  pool-A: tmp = bf16(relu(h)@pw^T)
__global__ __launch_bounds__(256) void k_gemm(
    const unsigned short* __restrict__ hb, const unsigned short* __restrict__ Wb,
    const float* __restrict__ db, const float* __restrict__ gb,
    float* __restrict__ accout, unsigned short* __restrict__ tmp,
    const int* __restrict__ idxp, const float* __restrict__ wscp,
    int eidx, int cin, int isA)
{
  int id = idxp[eidx];
  if (id == 8) return;                  // zero op
  bool pool = (id < 2);
  if (pool && !isA) return;             // B-edge pool has no GEMM
  bool grp = (id >= 5);
  int act = pool ? 0 : (grp ? id-5 : id-2);
  int K = grp ? (cin >> 2) : cin;

  int rowTile = blockIdx.x >> 3;        // 256 row tiles of 64
  int colTile = blockIdx.x & 7;         // 8 col tiles of 64
  int wave = threadIdx.x >> 6;
  int lane = threadIdx.x & 63;
  int wm = wave >> 1, wn = wave & 1;
  int row0 = rowTile*64 + wm*32;
  int col0 = colTile*64 + wn*32;
  int l16 = lane & 15, lq = lane >> 4;

  int g = grp ? (col0 >> 7) : 0;        // group of 128 output cols
  const unsigned short* A0 = hb + (long)(row0 + l16)*cin + (long)g*K;
  const unsigned short* A1 = A0 + (long)16*cin;
  const unsigned short* Bq0 = grp ? (Wb + (long)g*128*K + (long)((col0 & 127) + l16)*K)
                                  : (Wb + (long)(col0 + l16)*K);
  const unsigned short* Bq1 = Bq0 + (long)16*K;

  f32x4 acc00 = {0.f,0.f,0.f,0.f}, acc01 = acc00, acc10 = acc00, acc11 = acc00;

  for (int k0 = 0; k0 < K; k0 += 32){
    int kb = k0 + lq*8;
    short8 a0 = *(const short8*)(A0 + kb);
    short8 a1 = *(const short8*)(A1 + kb);
    if (pool){
      #pragma unroll
      for (int t=0;t<8;t++){
        a0[t] = (a0[t] < (short)0) ? (short)0 : a0[t];
        a1[t] = (a1[t] < (short)0) ? (short)0 : a1[t];
      }
    }
    short8 b0 = *(const short8*)(Bq0 + kb);
    short8 b1 = *(const short8*)(Bq1 + kb);
    acc00 = __builtin_amdgcn_mfma_f32_16x16x32_bf16(a0,b0,acc00,0,0,0);
    acc01 = __builtin_amdgcn_mfma_f32_16x16x32_bf16(a0,b1,acc01,0,0,0);
    acc10 = __builtin_amdgcn_mfma_f32_16x16x32_bf16(a1,b0,acc10,0,0,0);
    acc11 = __builtin_amdgcn_mfma_f32_16x16x32_bf16(a1,b1,acc11,0,0,0);
  }

  float we = wscp[eidx];
  #pragma unroll
  for (int sm=0;sm<2;sm++){
    #pragma unroll
    for (int sn=0;sn<2;sn++){
      f32x4 a = (sm==0) ? ((sn==0)?acc00:acc01) : ((sn==0)?acc10:acc11);
      int colb = col0 + sn*16 + l16;
      #pragma unroll
      for (int r=0;r<4;r++){
        int row = row0 + sm*16 + lq*4 + r;     // C/D layout: col=lane&15, row=(lane>>4)*4+reg
        long off = (long)row*CH + colb;
        float v = a[r];
        if (pool){
          tmp[off] = f2b(v);
        } else {
          v += grp ? gb[act*CH + colb] : db[act*CH + colb];
          v = (act==0) ? fmaxf(v,0.f) : (act==1) ? (1.f/(1.f+expf(-v))) : tanhf(v);
          accout[off] += we * v;
        }
      }
    }
  }
}

// ---------------- BN stats pass 1 over bf16 source ----------------
__global__ __launch_bounds__(512) void k_stats1(const unsigned short* __restrict__ S,
                        float* __restrict__ part,
                        const int* __restrict__ idxp, int eidx){
  if (idxp[eidx] >= 2) return;
  int c = threadIdx.x;
  const unsigned short* p = S + (long)blockIdx.x*128*CH + c;
  float s = 0.f, q = 0.f;
  for (int r = 0; r < 128; r++){ float v = b2f(p[(long)r*CH]); s += v; q += v*v; }
  long o = ((long)blockIdx.x*CH + c)*2;
  part[o] = s; part[o+1] = q;
}

// ---------------- BN stats pass 2 + composed scale ----------------
__global__ __launch_bounds__(512) void k_stats2(const float* __restrict__ part, float* __restrict__ alpha,
                        float* __restrict__ mval, const int* __restrict__ idxp, int eidx, int isA){
  int id = idxp[eidx]; if (id >= 2) return;
  int c = threadIdx.x;
  float s = 0.f, q = 0.f;
  for (int b = 0; b < 128; b++){ long o = ((long)b*CH + c)*2; s += part[o]; q += part[o+1]; }
  float m = s * (1.f/16384.f);
  float v = q * (1.f/16384.f) - m*m;
  v = fmaxf(v, 0.f);
  float al;
  if (isA){
    float s1 = rsqrtf(v + EPSBN);
    float vz = v / (v + EPSBN);          // var of BN1 output
    al = (id==0) ? (s1 * (1.f/9.f) * rsqrtf(vz*(1.f/81.f) + EPSBN))
                 : (s1 * rsqrtf(vz + EPSBN));
  } else {
    al = (id==0) ? ((1.f/9.f) * rsqrtf(v*(1.f/81.f) + EPSBN))
                 : rsqrtf(v + EPSBN);
  }
  alpha[c] = al; mval[c] = m;
}

// ---------------- pool finalize: acc += we*(S-m)*alpha, S bf16 ----------------
__global__ __launch_bounds__(256) void k_fin(const unsigned short* __restrict__ S, float* __restrict__ accout,
                     const float* __restrict__ alpha, const float* __restrict__ mval,
                     const int* __restrict__ idxp, const float* __restrict__ wscp, int eidx){
  if (idxp[eidx] >= 2) return;
  float we = wscp[eidx];
  long i4 = (long)blockIdx.x*blockDim.x + threadIdx.x;
  long base = i4*4;
  int c = (int)(base & (CH-1));
  ushort4v sv = ((const ushort4v*)S)[i4];
  float4 av = *(const float4*)(accout + base);
  av.x += we*(b2f(sv[0]) - mval[c+0])*alpha[c+0];
  av.y += we*(b2f(sv[1]) - mval[c+1])*alpha[c+1];
  av.z += we*(b2f(sv[2]) - mval[c+2])*alpha[c+2];
  av.w += we*(b2f(sv[3]) - mval[c+3])*alpha[c+3];
  *(float4*)(accout + base) = av;
}

extern "C" void kernel_launch(void* const* d_in, const int* in_sizes, int n_in,
                              void* d_out, int out_size, void* d_ws, size_t ws_size,
                              hipStream_t stream)
{
  const float* x   = (const float*)d_in[0];
  const float* ap  = (const float*)d_in[1];
  const float* gum = (const float*)d_in[2];
  const float* dwA = (const float*)d_in[3];
  const float* dbA = (const float*)d_in[4];
  const float* gwA = (const float*)d_in[5];
  const float* gbA = (const float*)d_in[6];
  const float* pwA = (const float*)d_in[7];
  const float* dwB = (const float*)d_in[8];
  const float* dbB = (const float*)d_in[9];
  const float* gwB = (const float*)d_in[10];
  const float* gbB = (const float*)d_in[11];
  float* out = (float*)d_out;

  char* ws = (char*)d_ws;
  size_t cur = 0;
  auto alloc = [&](size_t bytes)->void*{
    size_t o = cur; cur += (bytes + 255) & ~(size_t)255; return (void*)(ws + o);
  };
  int*   idx   = (int*)  alloc(21*sizeof(int));
  float* wsc   = (float*)alloc(21*sizeof(float));
  float* alpha = (float*)alloc(CH*sizeof(float));
  float* mval  = (float*)alloc(CH*sizeof(float));
  float* part  = (float*)alloc((size_t)128*CH*2*sizeof(float));
  unsigned short* Wb  = (unsigned short*)alloc((size_t)CH*1024*sizeof(unsigned short));
  unsigned short* tmp = (unsigned short*)alloc((size_t)BATCH*CH*sizeof(unsigned short));
  unsigned short* xb  = (unsigned short*)alloc((size_t)BATCH*1024*sizeof(unsigned short));
  unsigned short* sb[5];
  for (int i=0;i<5;i++)
    sb[i] = (unsigned short*)alloc((size_t)BATCH*CH*sizeof(unsigned short));

  if (cur > ws_size){
    // workspace too small: leave a distinctive sentinel and bail
    hipLaunchKernelGGL(k_sentinel, dim3(1), dim3(1), 0, stream, out);
    return;
  }

  // x -> bf16, and op-index selection
  hipLaunchKernelGGL(k_f2b4, dim3(BATCH*1024/4/256), dim3(256), 0, stream, x, xb, (long)BATCH*1024/4);
  hipLaunchKernelGGL(k_index, dim3(1), dim3(32), 0, stream, ap, gum, idx, wsc);

  const int eoff[6] = {0, 6, 11, 15, 18, 20};
  int a_ct = 0, b_ct = 0;
  for (int node = 1; node <= 6; node++){
    float* acc = out;   // d_out doubles as the per-node fp32 accumulator
    hipMemsetAsync(acc, 0, (size_t)BATCH*CH*sizeof(float), stream);
    for (int j = 0; j < node; j++){
      int e = eoff[j] + (node - (j+1));
      const float *dw,*dbp,*gw,*gbp,*pw; const unsigned short* srcB; int cin, isA;
      if (j == 0){
        isA = 1; cin = 1024;
        dw  = dwA + (long)a_ct*3*CH*1024;   dbp = dbA + (long)a_ct*3*CH;
        gw  = gwA + (long)a_ct*3*4*128*256; gbp = gbA + (long)a_ct*3*CH;
        pw  = pwA + (long)a_ct*2*CH*1024;
        srcB = xb;
        a_ct++;
      } else {
        isA = 0; cin = 512;
        dw  = dwB + (long)b_ct*3*CH*512;    dbp = dbB + (long)b_ct*3*CH;
        gw  = gwB + (long)b_ct*3*4*128*128; gbp = gbB + (long)b_ct*3*CH;
        pw  = nullptr;
        srcB = sb[j-1];
        b_ct++;
      }
      hipLaunchKernelGGL(k_wconv, dim3(1024), dim3(256), 0, stream, idx, e, isA, dw, pw, gw, cin, Wb);
      hipLaunchKernelGGL(k_gemm, dim3(2048), dim3(256), 0, stream,
                         srcB, Wb, dbp, gbp, acc, tmp, idx, wsc, e, cin, isA);
      const unsigned short* S = isA ? tmp : sb[j-1];   // bf16 source for BN ops
      hipLaunchKernelGGL(k_stats1, dim3(128), dim3(512), 0, stream, S, part, idx, e);
      hipLaunchKernelGGL(k_stats2, dim3(1), dim3(512), 0, stream, part, alpha, mval, idx, e, isA);
      hipLaunchKernelGGL(k_fin, dim3((BATCH*CH/4)/256), dim3(256), 0, stream, S, acc, alpha, mval, idx, wsc, e);
    }
    if (node < 6)
      hipLaunchKernelGGL(k_f2b4, dim3((BATCH*CH/4)/256), dim3(256), 0, stream,
                         out, sb[node-1], (long)BATCH*CH/4);
  }
}

// Round 3
// 1064.165 us; speedup vs baseline: 1.4607x; 1.4607x over previous
//
#include <hip/hip_runtime.h>

#define BATCH 16384
#define CH 512
#define EPSBN 1e-5f

typedef __attribute__((ext_vector_type(8))) short short8;
typedef __attribute__((ext_vector_type(4))) float f32x4;
typedef __attribute__((ext_vector_type(4))) unsigned short ushort4v;

#define GLOAD16(gp, lp) __builtin_amdgcn_global_load_lds( \
    (const __attribute__((address_space(1))) void*)(gp),  \
    (__attribute__((address_space(3))) void*)(lp), 16, 0, 0)

static __device__ __forceinline__ unsigned short f2b(float f){
  union { float f; unsigned u; } v; v.f = f;
  unsigned r = v.u + 0x7fffu + ((v.u >> 16) & 1u);
  return (unsigned short)(r >> 16);
}
static __device__ __forceinline__ float b2f(unsigned short u){
  union { unsigned u; float f; } v; v.u = ((unsigned)u) << 16; return v.f;
}

// ---------------- sentinel (ws too small) ----------------
__global__ void k_sentinel(float* out){ out[0] = 1.0e6f; }

// ---------------- index / wscale ----------------
__global__ void k_index(const float* __restrict__ ap, const float* __restrict__ gum,
                        int* __restrict__ idx, float* __restrict__ wsc){
  int e = threadIdx.x;
  if (e >= 21) return;
  const float* a = ap + e*9;
  const float* g = gum + e*9;
  float m = a[0];
  for (int o=1;o<9;o++) m = fmaxf(m, a[o]);
  float s = 0.f;
  for (int o=0;o<9;o++) s += expf(a[o]-m);
  float lse = m + logf(s);
  float lg[9]; float lm = -1e30f;
  for (int o=0;o<9;o++){ lg[o] = (a[o]-lse+g[o]) / 10.0f; lm = fmaxf(lm, lg[o]); }
  float ss = 0.f;
  for (int o=0;o<9;o++) ss += expf(lg[o]-lm);
  int bi = 0; float bp = -1.f;
  for (int o=0;o<9;o++){
    float p = expf(lg[o]-lm)/ss;
    if (p > bp){ bp = p; bi = o; }
  }
  idx[e] = bi;
  wsc[e] = (1.0f - bp) + bp;
}

// ---------------- fp32 -> bf16 (vector4, grid-stride) ----------------
__global__ void k_f2b4(const float* __restrict__ in, unsigned short* __restrict__ outp, long n4){
  long stride = (long)gridDim.x*blockDim.x;
  for (long i = (long)blockIdx.x*blockDim.x + threadIdx.x; i < n4; i += stride){
    const float4 v = ((const float4*)in)[i];
    ushort4v o;
    o[0] = f2b(v.x); o[1] = f2b(v.y); o[2] = f2b(v.z); o[3] = f2b(v.w);
    ((ushort4v*)outp)[i] = o;
  }
}

// ---------------- selected-weight convert ----------------
__global__ void k_wconv(const int* __restrict__ idxp, int eidx, int isA,
                        const float* __restrict__ dw, const float* __restrict__ pw,
                        const float* __restrict__ gw, int cin,
                        unsigned short* __restrict__ Wb){
  int id = idxp[eidx];
  const float* src; long n;
  if (id >= 2 && id <= 4){ n = (long)CH*cin; src = dw + (long)(id-2)*n; }
  else if (id <= 1 && isA){ n = (long)CH*cin; src = pw + (long)id*n; }
  else if (id >= 5 && id <= 7){ n = (long)CH*(cin/4); src = gw + (long)(id-5)*n; }
  else return;
  long stride = (long)gridDim.x*blockDim.x;
  for (long i = (long)blockIdx.x*blockDim.x + threadIdx.x; i < n; i += stride)
    Wb[i] = f2b(src[i]);
}

// ---------------- per-edge GEMM: 128x128 tile, BK=32, LDS-staged (m97 structure) ----------------
// dense/gdense: acc (=|+=) we*act(h@W^T + b);  pool-A: tmp = bf16(relu(h)@pw^T) [+ acc=0 if first]
// zero(first only): acc = 0
__global__ __launch_bounds__(256) void k_gemm(
    const unsigned short* __restrict__ hb, const unsigned short* __restrict__ Wb,
    const float* __restrict__ db, const float* __restrict__ gb,
    float* __restrict__ accout, unsigned short* __restrict__ tmp,
    const int* __restrict__ idxp, const float* __restrict__ wscp,
    int eidx, int cin, int isA, int first)
{
  int id = idxp[eidx];
  bool zero = (id == 8);
  if (zero && !first) return;
  bool pool = (id < 2);
  if (pool && !isA) return;
  bool grp = (id >= 5) && !zero;
  int act = pool ? 0 : (grp ? id - 5 : id - 2);
  int K = grp ? (cin >> 2) : cin;
  int nk = zero ? 0 : (K >> 5);

  // XCD-chunked swizzle over 512 blocks (512 % 8 == 0 -> bijective)
  int bid = blockIdx.x;
  int lg = (bid & 7) * 64 + (bid >> 3);
  int rowTile = lg >> 2, colTile = lg & 3;
  int row0 = rowTile * 128, col0 = colTile * 128;

  int t = threadIdx.x;
  int lane = t & 63, wave = t >> 6;
  int wm = wave >> 1, wn = wave & 1;
  int l16 = lane & 15, lq = lane >> 4;

  __shared__ unsigned short As[128*32];
  __shared__ unsigned short Bs[128*32];

  // group conv: colTile == group (BN=128 == group width); B layout [col][K] identical
  const unsigned short* Ag = hb + (long)(grp ? colTile * K : 0);
  const unsigned short* Bg = Wb + (long)col0 * K;

  int srow = t >> 2;            // 0..63
  int sc8  = (t & 3) << 3;      // k-chunk of 8
  const unsigned short* gA0 = Ag + (long)(row0 + srow)*cin + sc8;
  const unsigned short* gA1 = gA0 + (long)64*cin;
  const unsigned short* gB0 = Bg + (long)srow*K + sc8;
  const unsigned short* gB1 = gB0 + (long)64*K;
  unsigned short* lA0 = &As[t*8];
  unsigned short* lA1 = &As[2048 + t*8];
  unsigned short* lB0 = &Bs[t*8];
  unsigned short* lB1 = &Bs[2048 + t*8];

  f32x4 acc[4][4];
  #pragma unroll
  for (int m=0;m<4;m++)
    #pragma unroll
    for (int n=0;n<4;n++)
      acc[m][n] = (f32x4){0.f,0.f,0.f,0.f};

  const unsigned short* rA = &As[(wm*64 + l16)*32 + lq*8];
  const unsigned short* rB = &Bs[(wn*64 + l16)*32 + lq*8];

  for (int kt = 0; kt < nk; ++kt){
    if (kt) __syncthreads();
    long k0 = (long)kt * 32;
    GLOAD16(gA0 + k0, lA0);
    GLOAD16(gA1 + k0, lA1);
    GLOAD16(gB0 + k0, lB0);
    GLOAD16(gB1 + k0, lB1);
    __syncthreads();            // drains vmcnt(0) then barrier

    short8 a[4], b[4];
    #pragma unroll
    for (int m=0;m<4;m++) a[m] = *(const short8*)(rA + m*16*32);
    if (pool){
      #pragma unroll
      for (int m=0;m<4;m++)
        #pragma unroll
        for (int e2=0;e2<8;e2++)
          a[m][e2] = (a[m][e2] < (short)0) ? (short)0 : a[m][e2];
    }
    #pragma unroll
    for (int n=0;n<4;n++) b[n] = *(const short8*)(rB + n*16*32);
    #pragma unroll
    for (int m=0;m<4;m++)
      #pragma unroll
      for (int n=0;n<4;n++)
        acc[m][n] = __builtin_amdgcn_mfma_f32_16x16x32_bf16(a[m], b[n], acc[m][n], 0,0,0);
  }

  float we = wscp[eidx];
  #pragma unroll
  for (int m=0;m<4;m++){
    #pragma unroll
    for (int n=0;n<4;n++){
      int col  = col0 + wn*64 + n*16 + l16;
      int rowb = row0 + wm*64 + m*16 + lq*4;
      #pragma unroll
      for (int r=0;r<4;r++){
        long off = (long)(rowb + r)*CH + col;
        if (zero){
          accout[off] = 0.f;
        } else if (pool){
          tmp[off] = f2b(acc[m][n][r]);
          if (first) accout[off] = 0.f;
        } else {
          float v = acc[m][n][r] + (grp ? gb[act*CH + col] : db[act*CH + col]);
          v = (act==0) ? fmaxf(v, 0.f) : (act==1) ? (1.f/(1.f+expf(-v))) : tanhf(v);
          if (first) accout[off] = we * v;
          else       accout[off] += we * v;
        }
      }
    }
  }
}

// ---------------- BN stats pass 1 over bf16 source ----------------
__global__ __launch_bounds__(512) void k_stats1(const unsigned short* __restrict__ S,
                        float* __restrict__ part,
                        const int* __restrict__ idxp, int eidx){
  if (idxp[eidx] >= 2) return;
  int c = threadIdx.x;
  const unsigned short* p = S + (long)blockIdx.x*128*CH + c;
  float s = 0.f, q = 0.f;
  for (int r = 0; r < 128; r++){ float v = b2f(p[(long)r*CH]); s += v; q += v*v; }
  long o = ((long)blockIdx.x*CH + c)*2;
  part[o] = s; part[o+1] = q;
}

// ---------------- BN stats pass 2 + composed scale ----------------
__global__ __launch_bounds__(512) void k_stats2(const float* __restrict__ part, float* __restrict__ alpha,
                        float* __restrict__ mval, const int* __restrict__ idxp, int eidx, int isA){
  int id = idxp[eidx]; if (id >= 2) return;
  int c = threadIdx.x;
  float s = 0.f, q = 0.f;
  for (int b = 0; b < 128; b++){ long o = ((long)b*CH + c)*2; s += part[o]; q += part[o+1]; }
  float m = s * (1.f/16384.f);
  float v = q * (1.f/16384.f) - m*m;
  v = fmaxf(v, 0.f);
  float al;
  if (isA){
    float s1 = rsqrtf(v + EPSBN);
    float vz = v / (v + EPSBN);
    al = (id==0) ? (s1 * (1.f/9.f) * rsqrtf(vz*(1.f/81.f) + EPSBN))
                 : (s1 * rsqrtf(vz + EPSBN));
  } else {
    al = (id==0) ? ((1.f/9.f) * rsqrtf(v*(1.f/81.f) + EPSBN))
                 : rsqrtf(v + EPSBN);
  }
  alpha[c] = al; mval[c] = m;
}

// ---------------- pool finalize: acc += we*(S-m)*alpha (grid-stride) ----------------
__global__ __launch_bounds__(256) void k_fin(const unsigned short* __restrict__ S, float* __restrict__ accout,
                     const float* __restrict__ alpha, const float* __restrict__ mval,
                     const int* __restrict__ idxp, const float* __restrict__ wscp, int eidx){
  if (idxp[eidx] >= 2) return;
  float we = wscp[eidx];
  long n4 = (long)BATCH*CH/4;
  long stride = (long)gridDim.x*blockDim.x;
  for (long i4 = (long)blockIdx.x*blockDim.x + threadIdx.x; i4 < n4; i4 += stride){
    long base = i4*4;
    int c = (int)(base & (CH-1));
    ushort4v sv = ((const ushort4v*)S)[i4];
    float4 av = *(const float4*)(accout + base);
    av.x += we*(b2f(sv[0]) - mval[c+0])*alpha[c+0];
    av.y += we*(b2f(sv[1]) - mval[c+1])*alpha[c+1];
    av.z += we*(b2f(sv[2]) - mval[c+2])*alpha[c+2];
    av.w += we*(b2f(sv[3]) - mval[c+3])*alpha[c+3];
    *(float4*)(accout + base) = av;
  }
}

extern "C" void kernel_launch(void* const* d_in, const int* in_sizes, int n_in,
                              void* d_out, int out_size, void* d_ws, size_t ws_size,
                              hipStream_t stream)
{
  const float* x   = (const float*)d_in[0];
  const float* ap  = (const float*)d_in[1];
  const float* gum = (const float*)d_in[2];
  const float* dwA = (const float*)d_in[3];
  const float* dbA = (const float*)d_in[4];
  const float* gwA = (const float*)d_in[5];
  const float* gbA = (const float*)d_in[6];
  const float* pwA = (const float*)d_in[7];
  const float* dwB = (const float*)d_in[8];
  const float* dbB = (const float*)d_in[9];
  const float* gwB = (const float*)d_in[10];
  const float* gbB = (const float*)d_in[11];
  float* out = (float*)d_out;

  char* ws = (char*)d_ws;
  size_t cur = 0;
  auto alloc = [&](size_t bytes)->void*{
    size_t o = cur; cur += (bytes + 255) & ~(size_t)255; return (void*)(ws + o);
  };
  int*   idx   = (int*)  alloc(21*sizeof(int));
  float* wsc   = (float*)alloc(21*sizeof(float));
  float* alpha = (float*)alloc(CH*sizeof(float));
  float* mval  = (float*)alloc(CH*sizeof(float));
  float* part  = (float*)alloc((size_t)128*CH*2*sizeof(float));
  unsigned short* Wb  = (unsigned short*)alloc((size_t)CH*1024*sizeof(unsigned short));
  unsigned short* tmp = (unsigned short*)alloc((size_t)BATCH*CH*sizeof(unsigned short));
  unsigned short* xb  = (unsigned short*)alloc((size_t)BATCH*1024*sizeof(unsigned short));
  unsigned short* sb[5];
  for (int i=0;i<5;i++)
    sb[i] = (unsigned short*)alloc((size_t)BATCH*CH*sizeof(unsigned short));

  if (cur > ws_size){
    hipLaunchKernelGGL(k_sentinel, dim3(1), dim3(1), 0, stream, out);
    return;
  }

  hipLaunchKernelGGL(k_f2b4, dim3(2048), dim3(256), 0, stream, x, xb, (long)BATCH*1024/4);
  hipLaunchKernelGGL(k_index, dim3(1), dim3(32), 0, stream, ap, gum, idx, wsc);

  const int eoff[6] = {0, 6, 11, 15, 18, 20};
  int a_ct = 0, b_ct = 0;
  for (int node = 1; node <= 6; node++){
    float* acc = out;   // d_out doubles as the per-node fp32 accumulator
    for (int j = 0; j < node; j++){
      int e = eoff[j] + (node - (j+1));
      const float *dw,*dbp,*gw,*gbp,*pw; const unsigned short* srcB; int cin, isA;
      if (j == 0){
        isA = 1; cin = 1024;
        dw  = dwA + (long)a_ct*3*CH*1024;   dbp = dbA + (long)a_ct*3*CH;
        gw  = gwA + (long)a_ct*3*4*128*256; gbp = gbA + (long)a_ct*3*CH;
        pw  = pwA + (long)a_ct*2*CH*1024;
        srcB = xb;
        a_ct++;
      } else {
        isA = 0; cin = 512;
        dw  = dwB + (long)b_ct*3*CH*512;    dbp = dbB + (long)b_ct*3*CH;
        gw  = gwB + (long)b_ct*3*4*128*128; gbp = gbB + (long)b_ct*3*CH;
        pw  = nullptr;
        srcB = sb[j-1];
        b_ct++;
      }
      hipLaunchKernelGGL(k_wconv, dim3(1024), dim3(256), 0, stream, idx, e, isA, dw, pw, gw, cin, Wb);
      hipLaunchKernelGGL(k_gemm, dim3(512), dim3(256), 0, stream,
                         srcB, Wb, dbp, gbp, acc, tmp, idx, wsc, e, cin, isA, (j==0)?1:0);
      const unsigned short* S = isA ? tmp : sb[j-1];   // bf16 source for BN ops
      hipLaunchKernelGGL(k_stats1, dim3(128), dim3(512), 0, stream, S, part, idx, e);
      hipLaunchKernelGGL(k_stats2, dim3(1), dim3(512), 0, stream, part, alpha, mval, idx, e, isA);
      hipLaunchKernelGGL(k_fin, dim3(2048), dim3(256), 0, stream, S, acc, alpha, mval, idx, wsc, e);
    }
    if (node < 6)
      hipLaunchKernelGGL(k_f2b4, dim3(2048), dim3(256), 0, stream,
                         out, sb[node-1], (long)BATCH*CH/4);
  }
}

// Round 4
// 550.028 us; speedup vs baseline: 2.8261x; 1.9347x over previous
//
#include <hip/hip_runtime.h>

#define BATCH 16384
#define CH 512
#define EPSBN 1e-5f

typedef __attribute__((ext_vector_type(8))) short short8;
typedef __attribute__((ext_vector_type(4))) float f32x4;
typedef __attribute__((ext_vector_type(4))) unsigned short ushort4v;

#define GLOAD16(gp, lp) __builtin_amdgcn_global_load_lds( \
    (const __attribute__((address_space(1))) void*)(gp),  \
    (__attribute__((address_space(3))) void*)(lp), 16, 0, 0)

// edge table: etab[node-1][j] = edge id; bct[e] = B-weight counter
__constant__ int d_etab[6][6] = {
  {0,0,0,0,0,0},
  {1,6,0,0,0,0},
  {2,7,11,0,0,0},
  {3,8,12,15,0,0},
  {4,9,13,16,18,0},
  {5,10,14,17,19,20}};
__constant__ int d_bct[21] = {0,0,0,0,0,0, 0,1,3,6,10, 2,4,7,11, 5,8,12, 9,13, 14};

static __device__ __forceinline__ long woff(int e){
  return (e < 6) ? (long)e*524288 : 3145728L + (long)d_bct[e]*262144;
}

static __device__ __forceinline__ unsigned short f2b(float f){
  union { float f; unsigned u; } v; v.f = f;
  unsigned r = v.u + 0x7fffu + ((v.u >> 16) & 1u);
  return (unsigned short)(r >> 16);
}
static __device__ __forceinline__ float b2f(unsigned short u){
  union { unsigned u; float f; } v; v.u = ((unsigned)u) << 16; return v.f;
}

__global__ void k_sentinel(float* out){ out[0] = 1.0e6f; }

// ---------------- index / wscale ----------------
__global__ void k_index(const float* __restrict__ ap, const float* __restrict__ gum,
                        int* __restrict__ idx, float* __restrict__ wsc){
  int e = threadIdx.x;
  if (e >= 21) return;
  const float* a = ap + e*9;
  const float* g = gum + e*9;
  float m = a[0];
  for (int o=1;o<9;o++) m = fmaxf(m, a[o]);
  float s = 0.f;
  for (int o=0;o<9;o++) s += expf(a[o]-m);
  float lse = m + logf(s);
  float lg[9]; float lm = -1e30f;
  for (int o=0;o<9;o++){ lg[o] = (a[o]-lse+g[o]) / 10.0f; lm = fmaxf(lm, lg[o]); }
  float ss = 0.f;
  for (int o=0;o<9;o++) ss += expf(lg[o]-lm);
  int bi = 0; float bp = -1.f;
  for (int o=0;o<9;o++){
    float p = expf(lg[o]-lm)/ss;
    if (p > bp){ bp = p; bi = o; }
  }
  idx[e] = bi;
  wsc[e] = (1.0f - bp) + bp;
}

// ---------------- fp32 -> bf16 (vector4, grid-stride) ----------------
__global__ void k_f2b4(const float* __restrict__ in, unsigned short* __restrict__ outp, long n4){
  long stride = (long)gridDim.x*blockDim.x;
  for (long i = (long)blockIdx.x*blockDim.x + threadIdx.x; i < n4; i += stride){
    const float4 v = ((const float4*)in)[i];
    ushort4v o;
    o[0] = f2b(v.x); o[1] = f2b(v.y); o[2] = f2b(v.z); o[3] = f2b(v.w);
    ((ushort4v*)outp)[i] = o;
  }
}

// ---------------- all selected weights -> bf16 slots ----------------
__global__ void k_wconv_all(const int* __restrict__ idxp,
                            const float* __restrict__ dwA, const float* __restrict__ pwA,
                            const float* __restrict__ gwA, const float* __restrict__ dwB,
                            const float* __restrict__ gwB,
                            unsigned short* __restrict__ Wball){
  int e = blockIdx.x >> 7;          // 21 edges x 128 blocks
  int blk = blockIdx.x & 127;
  int id = idxp[e];
  const float* src; long n;
  if (e < 6){
    int a = e;
    if (id >= 2 && id <= 4){ n = 524288; src = dwA + ((long)a*3 + (id-2))*n; }
    else if (id < 2)       { n = 524288; src = pwA + ((long)a*2 + id)*n; }
    else if (id <= 7)      { n = 131072; src = gwA + ((long)a*3 + (id-5))*131072; }
    else return;
  } else {
    int b = d_bct[e];
    if (id >= 2 && id <= 4)     { n = 262144; src = dwB + ((long)b*3 + (id-2))*n; }
    else if (id >= 5 && id <= 7){ n = 65536;  src = gwB + ((long)b*3 + (id-5))*65536; }
    else return;
  }
  unsigned short* dst = Wball + woff(e);
  long n4 = n >> 2;
  long stride = 128*256;
  for (long i = (long)blk*256 + threadIdx.x; i < n4; i += stride){
    const float4 v = ((const float4*)src)[i];
    ushort4v o;
    o[0] = f2b(v.x); o[1] = f2b(v.y); o[2] = f2b(v.z); o[3] = f2b(v.w);
    ((ushort4v*)dst)[i] = o;
  }
}

// ---------------- pool-A pre-GEMM: tmp = bf16(relu(x) @ pw^T) ----------------
// 128x64 tile, BK=32, 4 waves (2x2), runs only if node's A-edge selected pool
__global__ __launch_bounds__(256) void k_gemm_pool(
    int node, const unsigned short* __restrict__ xb,
    const unsigned short* __restrict__ Wball, unsigned short* __restrict__ tmp,
    const int* __restrict__ idxp)
{
  int e = node - 1;
  int id = idxp[e];
  if (id >= 2) return;

  int bid = blockIdx.x;
  int lg = (bid & 7) * 128 + (bid >> 3);
  int rowTile = lg >> 3, colTile = lg & 7;
  int row0 = rowTile * 128, col0 = colTile * 64;

  int t = threadIdx.x;
  int lane = t & 63, wave = t >> 6;
  int wm = wave >> 1, wn = wave & 1;
  int l16 = lane & 15, lq = lane >> 4;

  __shared__ unsigned short As[128*32];
  __shared__ unsigned short Bs[64*32];

  const unsigned short* W = Wball + (long)e*524288 + (long)col0*1024;

  f32x4 acc[4][2];
  #pragma unroll
  for (int m=0;m<4;m++){ acc[m][0]=(f32x4){0,0,0,0}; acc[m][1]=(f32x4){0,0,0,0}; }

  const unsigned short* rA = &As[(wm*64 + l16)*32 + lq*8];
  const unsigned short* rB = &Bs[(wn*32 + l16)*32 + lq*8];

  int c0 = t, c1 = 256 + t;
  const unsigned short* gA0 = xb + (long)(row0 + (c0>>2))*1024 + ((c0&3)*8);
  const unsigned short* gA1 = xb + (long)(row0 + (c1>>2))*1024 + ((c1&3)*8);
  const unsigned short* gB  = W  + (long)(t>>2)*1024 + ((t&3)*8);
  unsigned short* lA0 = &As[c0*8];
  unsigned short* lA1 = &As[c1*8];
  unsigned short* lB  = &Bs[t*8];

  for (int kt = 0; kt < 32; ++kt){
    if (kt) __syncthreads();
    int k0 = kt*32;
    GLOAD16(gA0 + k0, lA0);
    GLOAD16(gA1 + k0, lA1);
    GLOAD16(gB  + k0, lB);
    __syncthreads();
    short8 a[4], b[2];
    #pragma unroll
    for (int m=0;m<4;m++){
      a[m] = *(const short8*)(rA + m*16*32);
      #pragma unroll
      for (int q=0;q<8;q++) a[m][q] = (a[m][q] < (short)0) ? (short)0 : a[m][q];
    }
    #pragma unroll
    for (int n=0;n<2;n++) b[n] = *(const short8*)(rB + n*16*32);
    #pragma unroll
    for (int m=0;m<4;m++)
      #pragma unroll
      for (int n=0;n<2;n++)
        acc[m][n] = __builtin_amdgcn_mfma_f32_16x16x32_bf16(a[m], b[n], acc[m][n], 0,0,0);
  }

  #pragma unroll
  for (int n=0;n<2;n++){
    int cn = col0 + wn*32 + n*16 + l16;
    #pragma unroll
    for (int m=0;m<4;m++)
      #pragma unroll
      for (int r=0;r<4;r++){
        int row = row0 + wm*64 + m*16 + lq*4 + r;
        tmp[(long)row*CH + cn] = f2b(acc[m][n][r]);
      }
  }
}

// ---------------- node stats pass1: partials for every pool edge of node ----------------
__global__ __launch_bounds__(512) void k_stats_node(
    int node, const unsigned short* __restrict__ tmp,
    const unsigned short* __restrict__ sb0, const unsigned short* __restrict__ sb1,
    const unsigned short* __restrict__ sb2, const unsigned short* __restrict__ sb3,
    const unsigned short* __restrict__ sb4,
    float* __restrict__ part, const int* __restrict__ idxp)
{
  int c = threadIdx.x;
  for (int jj = 0; jj < node; ++jj){
    int e = d_etab[node-1][jj];
    if (idxp[e] >= 2) continue;
    const unsigned short* S;
    switch(jj){ case 0: S=tmp; break; case 1: S=sb0; break; case 2: S=sb1; break;
                case 3: S=sb2; break; case 4: S=sb3; break; default: S=sb4; }
    const unsigned short* p = S + (long)blockIdx.x*128*CH + c;
    float s = 0.f, q = 0.f;
    for (int r = 0; r < 128; r++){ float v = b2f(p[(long)r*CH]); s += v; q += v*v; }
    long o = (((long)jj*128 + blockIdx.x)*CH + c)*2;
    part[o] = s; part[o+1] = q;
  }
}

// ---------------- node stats pass2: per-edge alpha/mval ----------------
__global__ __launch_bounds__(512) void k_stats2_node(
    int node, const float* __restrict__ part,
    float* __restrict__ alphaAll, float* __restrict__ mvalAll,
    const int* __restrict__ idxp)
{
  int c = threadIdx.x;
  for (int jj = 0; jj < node; ++jj){
    int e = d_etab[node-1][jj];
    int id = idxp[e];
    if (id >= 2) continue;
    float s = 0.f, q = 0.f;
    for (int b = 0; b < 128; b++){
      long o = (((long)jj*128 + b)*CH + c)*2;
      s += part[o]; q += part[o+1];
    }
    float m = s * (1.f/16384.f);
    float v = q * (1.f/16384.f) - m*m;
    v = fmaxf(v, 0.f);
    float al;
    if (jj == 0){
      float s1 = rsqrtf(v + EPSBN);
      float vz = v / (v + EPSBN);
      al = (id==0) ? (s1 * (1.f/9.f) * rsqrtf(vz*(1.f/81.f) + EPSBN))
                   : (s1 * rsqrtf(vz + EPSBN));
    } else {
      al = (id==0) ? ((1.f/9.f) * rsqrtf(v*(1.f/81.f) + EPSBN))
                   : rsqrtf(v + EPSBN);
    }
    alphaAll[(long)e*CH + c] = al;
    mvalAll[(long)e*CH + c] = m;
  }
}

// ---------------- fused per-node kernel: all edges, register accumulation ----------------
__global__ __launch_bounds__(256) void k_fused(
    int node,
    const unsigned short* __restrict__ xb,
    const unsigned short* __restrict__ sb0, const unsigned short* __restrict__ sb1,
    const unsigned short* __restrict__ sb2, const unsigned short* __restrict__ sb3,
    const unsigned short* __restrict__ sb4,
    unsigned short* __restrict__ sbout, float* __restrict__ outf,
    const unsigned short* __restrict__ tmp, const unsigned short* __restrict__ Wball,
    const float* __restrict__ dbA, const float* __restrict__ gbA,
    const float* __restrict__ dbB, const float* __restrict__ gbB,
    const float* __restrict__ alphaAll, const float* __restrict__ mvalAll,
    const int* __restrict__ idxp, const float* __restrict__ wscp)
{
  int bid = blockIdx.x;
  int lg = (bid & 7) * 128 + (bid >> 3);
  int rowTile = lg >> 3, colTile = lg & 7;
  int row0 = rowTile * 128, col0 = colTile * 64;

  int t = threadIdx.x;
  int lane = t & 63, wave = t >> 6;
  int wm = wave >> 1, wn = wave & 1;
  int l16 = lane & 15, lq = lane >> 4;

  __shared__ unsigned short As[128*32];
  __shared__ unsigned short Bs[64*32];

  const unsigned short* rA = &As[(wm*64 + l16)*32 + lq*8];
  const unsigned short* rB = &Bs[(wn*32 + l16)*32 + lq*8];

  f32x4 facc[4][2];
  #pragma unroll
  for (int m=0;m<4;m++){ facc[m][0]=(f32x4){0,0,0,0}; facc[m][1]=(f32x4){0,0,0,0}; }

  for (int jj = 0; jj < node; ++jj){
    int e = d_etab[node-1][jj];
    int id = idxp[e];
    if (id == 8) continue;
    float we = wscp[e];

    const unsigned short* st;
    switch(jj){ case 0: st=xb; break; case 1: st=sb0; break; case 2: st=sb1; break;
                case 3: st=sb2; break; case 4: st=sb3; break; default: st=sb4; }

    if (id < 2){
      // pool: facc += we*(S-m)*alpha  (S = tmp for A-edge, state for B-edge)
      const unsigned short* S = (jj==0) ? tmp : st;
      const float* al = alphaAll + (long)e*CH;
      const float* mv = mvalAll + (long)e*CH;
      #pragma unroll
      for (int n=0;n<2;n++){
        int cn = col0 + wn*32 + n*16 + l16;
        float a_n = al[cn], m_n = mv[cn];
        #pragma unroll
        for (int m=0;m<4;m++){
          int rowb = row0 + wm*64 + m*16 + lq*4;
          #pragma unroll
          for (int r=0;r<4;r++)
            facc[m][n][r] += we * (b2f(S[(long)(rowb+r)*CH + cn]) - m_n) * a_n;
        }
      }
      continue;
    }

    // GEMM edge (dense or group)
    bool grp = (id >= 5);
    int cin = (jj==0) ? 1024 : 512;
    int K = grp ? (cin >> 2) : cin;
    int act = grp ? id - 5 : id - 2;
    const unsigned short* Abase = st + (grp ? (long)(col0 >> 7)*K : 0);
    const unsigned short* Wbase = Wball + woff(e) + (long)col0*K;
    const float* bias;
    if (jj == 0) bias = (grp ? gbA : dbA) + ((long)e*3 + act)*CH;
    else         bias = (grp ? gbB : dbB) + ((long)d_bct[e]*3 + act)*CH;

    int c0 = t, c1 = 256 + t;
    const unsigned short* gA0 = Abase + (long)(row0 + (c0>>2))*cin + ((c0&3)*8);
    const unsigned short* gA1 = Abase + (long)(row0 + (c1>>2))*cin + ((c1&3)*8);
    const unsigned short* gB  = Wbase + (long)(t>>2)*K + ((t&3)*8);
    unsigned short* lA0 = &As[c0*8];
    unsigned short* lA1 = &As[c1*8];
    unsigned short* lB  = &Bs[t*8];

    f32x4 acc[4][2];
    #pragma unroll
    for (int m=0;m<4;m++){ acc[m][0]=(f32x4){0,0,0,0}; acc[m][1]=(f32x4){0,0,0,0}; }

    int nk = K >> 5;
    __syncthreads();   // protect LDS from previous edge's readers
    for (int kt = 0; kt < nk; ++kt){
      if (kt) __syncthreads();
      int k0 = kt*32;
      GLOAD16(gA0 + k0, lA0);
      GLOAD16(gA1 + k0, lA1);
      GLOAD16(gB  + k0, lB);
      __syncthreads();
      short8 a[4], b[2];
      #pragma unroll
      for (int m=0;m<4;m++) a[m] = *(const short8*)(rA + m*16*32);
      #pragma unroll
      for (int n=0;n<2;n++) b[n] = *(const short8*)(rB + n*16*32);
      #pragma unroll
      for (int m=0;m<4;m++)
        #pragma unroll
        for (int n=0;n<2;n++)
          acc[m][n] = __builtin_amdgcn_mfma_f32_16x16x32_bf16(a[m], b[n], acc[m][n], 0,0,0);
    }

    #pragma unroll
    for (int n=0;n<2;n++){
      int cn = col0 + wn*32 + n*16 + l16;
      float bv = bias[cn];
      #pragma unroll
      for (int m=0;m<4;m++)
        #pragma unroll
        for (int r=0;r<4;r++){
          float v = acc[m][n][r] + bv;
          v = (act==0) ? fmaxf(v, 0.f) : (act==1) ? (1.f/(1.f+expf(-v))) : tanhf(v);
          facc[m][n][r] += we * v;
        }
    }
  }

  // epilogue: write state (bf16) or final output (fp32)
  #pragma unroll
  for (int n=0;n<2;n++){
    int cn = col0 + wn*32 + n*16 + l16;
    #pragma unroll
    for (int m=0;m<4;m++){
      int rowb = row0 + wm*64 + m*16 + lq*4;
      #pragma unroll
      for (int r=0;r<4;r++){
        long off = (long)(rowb+r)*CH + cn;
        if (node == 6) outf[off] = facc[m][n][r];
        else           sbout[off] = f2b(facc[m][n][r]);
      }
    }
  }
}

extern "C" void kernel_launch(void* const* d_in, const int* in_sizes, int n_in,
                              void* d_out, int out_size, void* d_ws, size_t ws_size,
                              hipStream_t stream)
{
  const float* x   = (const float*)d_in[0];
  const float* ap  = (const float*)d_in[1];
  const float* gum = (const float*)d_in[2];
  const float* dwA = (const float*)d_in[3];
  const float* dbA = (const float*)d_in[4];
  const float* gwA = (const float*)d_in[5];
  const float* gbA = (const float*)d_in[6];
  const float* pwA = (const float*)d_in[7];
  const float* dwB = (const float*)d_in[8];
  const float* dbB = (const float*)d_in[9];
  const float* gwB = (const float*)d_in[10];
  const float* gbB = (const float*)d_in[11];
  float* out = (float*)d_out;

  char* ws = (char*)d_ws;
  size_t cur = 0;
  auto alloc = [&](size_t bytes)->void*{
    size_t o = cur; cur += (bytes + 255) & ~(size_t)255; return (void*)(ws + o);
  };
  int*   idx      = (int*)  alloc(21*sizeof(int));
  float* wsc      = (float*)alloc(21*sizeof(float));
  float* alphaAll = (float*)alloc((size_t)21*CH*sizeof(float));
  float* mvalAll  = (float*)alloc((size_t)21*CH*sizeof(float));
  float* part     = (float*)alloc((size_t)6*128*CH*2*sizeof(float));
  unsigned short* Wball = (unsigned short*)alloc((size_t)7077888*sizeof(unsigned short));
  unsigned short* tmp   = (unsigned short*)alloc((size_t)BATCH*CH*sizeof(unsigned short));
  unsigned short* xb    = (unsigned short*)alloc((size_t)BATCH*1024*sizeof(unsigned short));
  unsigned short* sb[5];
  for (int i=0;i<5;i++)
    sb[i] = (unsigned short*)alloc((size_t)BATCH*CH*sizeof(unsigned short));

  if (cur > ws_size){
    hipLaunchKernelGGL(k_sentinel, dim3(1), dim3(1), 0, stream, out);
    return;
  }

  hipLaunchKernelGGL(k_f2b4, dim3(2048), dim3(256), 0, stream, x, xb, (long)BATCH*1024/4);
  hipLaunchKernelGGL(k_index, dim3(1), dim3(32), 0, stream, ap, gum, idx, wsc);
  hipLaunchKernelGGL(k_wconv_all, dim3(21*128), dim3(256), 0, stream,
                     idx, dwA, pwA, gwA, dwB, gwB, Wball);

  for (int node = 1; node <= 6; node++){
    hipLaunchKernelGGL(k_gemm_pool, dim3(1024), dim3(256), 0, stream,
                       node, xb, Wball, tmp, idx);
    hipLaunchKernelGGL(k_stats_node, dim3(128), dim3(512), 0, stream,
                       node, tmp, sb[0], sb[1], sb[2], sb[3], sb[4], part, idx);
    hipLaunchKernelGGL(k_stats2_node, dim3(1), dim3(512), 0, stream,
                       node, part, alphaAll, mvalAll, idx);
    hipLaunchKernelGGL(k_fused, dim3(1024), dim3(256), 0, stream,
                       node, xb, sb[0], sb[1], sb[2], sb[3], sb[4],
                       (node < 6) ? sb[node-1] : sb[0], out,
                       tmp, Wball, dbA, gbA, dbB, gbB,
                       alphaAll, mvalAll, idx, wsc);
  }
}

// Round 5
// 525.680 us; speedup vs baseline: 2.9570x; 1.0463x over previous
//
#include <hip/hip_runtime.h>

#define BATCH 16384
#define CH 512
#define EPSBN 1e-5f

typedef __attribute__((ext_vector_type(8))) short short8;
typedef __attribute__((ext_vector_type(4))) float f32x4;
typedef __attribute__((ext_vector_type(4))) unsigned short ushort4v;

#define GLOAD16(gp, lp) __builtin_amdgcn_global_load_lds( \
    (const __attribute__((address_space(1))) void*)(gp),  \
    (__attribute__((address_space(3))) void*)(lp), 16, 0, 0)

// edge table: etab[node-1][j] = edge id; bct[e] = B-weight counter
__constant__ int d_etab[6][6] = {
  {0,0,0,0,0,0},
  {1,6,0,0,0,0},
  {2,7,11,0,0,0},
  {3,8,12,15,0,0},
  {4,9,13,16,18,0},
  {5,10,14,17,19,20}};
__constant__ int d_bct[21] = {0,0,0,0,0,0, 0,1,3,6,10, 2,4,7,11, 5,8,12, 9,13, 14};

static __device__ __forceinline__ long woff(int e){
  return (e < 6) ? (long)e*524288 : 3145728L + (long)d_bct[e]*262144;
}

static __device__ __forceinline__ unsigned short f2b(float f){
  union { float f; unsigned u; } v; v.f = f;
  unsigned r = v.u + 0x7fffu + ((v.u >> 16) & 1u);
  return (unsigned short)(r >> 16);
}
static __device__ __forceinline__ float b2f(unsigned short u){
  union { unsigned u; float f; } v; v.u = ((unsigned)u) << 16; return v.f;
}

__global__ void k_sentinel(float* out){ out[0] = 1.0e6f; }

// ---------------- index / wscale ----------------
__global__ void k_index(const float* __restrict__ ap, const float* __restrict__ gum,
                        int* __restrict__ idx, float* __restrict__ wsc){
  int e = threadIdx.x;
  if (e >= 21) return;
  const float* a = ap + e*9;
  const float* g = gum + e*9;
  float m = a[0];
  for (int o=1;o<9;o++) m = fmaxf(m, a[o]);
  float s = 0.f;
  for (int o=0;o<9;o++) s += expf(a[o]-m);
  float lse = m + logf(s);
  float lg[9]; float lm = -1e30f;
  for (int o=0;o<9;o++){ lg[o] = (a[o]-lse+g[o]) / 10.0f; lm = fmaxf(lm, lg[o]); }
  float ss = 0.f;
  for (int o=0;o<9;o++) ss += expf(lg[o]-lm);
  int bi = 0; float bp = -1.f;
  for (int o=0;o<9;o++){
    float p = expf(lg[o]-lm)/ss;
    if (p > bp){ bp = p; bi = o; }
  }
  idx[e] = bi;
  wsc[e] = (1.0f - bp) + bp;
}

// ---------------- fp32 -> bf16 (vector4, grid-stride) ----------------
__global__ void k_f2b4(const float* __restrict__ in, unsigned short* __restrict__ outp, long n4){
  long stride = (long)gridDim.x*blockDim.x;
  for (long i = (long)blockIdx.x*blockDim.x + threadIdx.x; i < n4; i += stride){
    const float4 v = ((const float4*)in)[i];
    ushort4v o;
    o[0] = f2b(v.x); o[1] = f2b(v.y); o[2] = f2b(v.z); o[3] = f2b(v.w);
    ((ushort4v*)outp)[i] = o;
  }
}

// ---------------- all selected weights -> bf16 slots ----------------
__global__ void k_wconv_all(const int* __restrict__ idxp,
                            const float* __restrict__ dwA, const float* __restrict__ pwA,
                            const float* __restrict__ gwA, const float* __restrict__ dwB,
                            const float* __restrict__ gwB,
                            unsigned short* __restrict__ Wball){
  int e = blockIdx.x >> 7;          // 21 edges x 128 blocks
  int blk = blockIdx.x & 127;
  int id = idxp[e];
  const float* src; long n;
  if (e < 6){
    int a = e;
    if (id >= 2 && id <= 4){ n = 524288; src = dwA + ((long)a*3 + (id-2))*n; }
    else if (id < 2)       { n = 524288; src = pwA + ((long)a*2 + id)*n; }
    else if (id <= 7)      { n = 131072; src = gwA + ((long)a*3 + (id-5))*131072; }
    else return;
  } else {
    int b = d_bct[e];
    if (id >= 2 && id <= 4)     { n = 262144; src = dwB + ((long)b*3 + (id-2))*n; }
    else if (id >= 5 && id <= 7){ n = 65536;  src = gwB + ((long)b*3 + (id-5))*65536; }
    else return;
  }
  unsigned short* dst = Wball + woff(e);
  long n4 = n >> 2;
  long stride = 128*256;
  for (long i = (long)blk*256 + threadIdx.x; i < n4; i += stride){
    const float4 v = ((const float4*)src)[i];
    ushort4v o;
    o[0] = f2b(v.x); o[1] = f2b(v.y); o[2] = f2b(v.z); o[3] = f2b(v.w);
    ((ushort4v*)dst)[i] = o;
  }
}

// ---------------- pool-A pre-GEMM: tmp = bf16(relu(x) @ pw^T) ----------------
// 128x64 tile, BK=32, double-buffered prefetch, swizzled LDS (conflict-free)
__global__ __launch_bounds__(256) void k_gemm_pool(
    int node, const unsigned short* __restrict__ xb,
    const unsigned short* __restrict__ Wball, unsigned short* __restrict__ tmp,
    const int* __restrict__ idxp)
{
  int e = node - 1;
  int id = idxp[e];
  if (id >= 2) return;

  int bid = blockIdx.x;
  int lg = (bid & 7) * 128 + (bid >> 3);
  int rowTile = lg >> 3, colTile = lg & 7;
  int row0 = rowTile * 128, col0 = colTile * 64;

  int t = threadIdx.x;
  int lane = t & 63, wave = t >> 6;
  int wm = wave >> 1, wn = wave & 1;
  int l16 = lane & 15, lq = lane >> 4;

  __shared__ unsigned short LDS[12288];   // A0[4096] A1[4096] B0[2048] B1[2048]

  int ra = t >> 2;
  int ca = (((t & 3) ^ ((ra >> 1) & 3)) << 3);
  int aoff[4], boff[2];
  #pragma unroll
  for (int m=0;m<4;m++){ int R = wm*64 + m*16 + l16; aoff[m] = R*32 + ((lq ^ ((R>>1)&3))<<3); }
  #pragma unroll
  for (int n=0;n<2;n++){ int C = wn*32 + n*16 + l16; boff[n] = C*32 + ((lq ^ ((C>>1)&3))<<3); }

  const unsigned short* W = Wball + (long)e*524288 + (long)col0*1024;
  const unsigned short* gA0 = xb + (long)(row0 + ra)*1024 + ca;
  const unsigned short* gA1 = xb + (long)(row0 + 64 + ra)*1024 + ca;
  const unsigned short* gB  = W  + (long)ra*1024 + ca;

  f32x4 acc[4][2];
  #pragma unroll
  for (int m=0;m<4;m++){ acc[m][0]=(f32x4){0,0,0,0}; acc[m][1]=(f32x4){0,0,0,0}; }

  GLOAD16(gA0, &LDS[t*8]);
  GLOAD16(gA1, &LDS[2048 + t*8]);
  GLOAD16(gB,  &LDS[8192 + t*8]);
  __syncthreads();

  int buf = 0;
  for (int kt = 0; kt < 32; ++kt){
    int nb = buf ^ 1;
    if (kt+1 < 32){
      long kk = (long)(kt+1)*32;
      GLOAD16(gA0 + kk, &LDS[nb*4096 + t*8]);
      GLOAD16(gA1 + kk, &LDS[nb*4096 + 2048 + t*8]);
      GLOAD16(gB  + kk, &LDS[8192 + nb*2048 + t*8]);
    }
    const unsigned short* pA = &LDS[buf*4096];
    const unsigned short* pB = &LDS[8192 + buf*2048];
    short8 a[4], b[2];
    #pragma unroll
    for (int m=0;m<4;m++){
      a[m] = *(const short8*)(pA + aoff[m]);
      #pragma unroll
      for (int q=0;q<8;q++) a[m][q] = (a[m][q] < (short)0) ? (short)0 : a[m][q];
    }
    #pragma unroll
    for (int n=0;n<2;n++) b[n] = *(const short8*)(pB + boff[n]);
    #pragma unroll
    for (int m=0;m<4;m++)
      #pragma unroll
      for (int n=0;n<2;n++)
        acc[m][n] = __builtin_amdgcn_mfma_f32_16x16x32_bf16(a[m], b[n], acc[m][n], 0,0,0);
    __syncthreads();
    buf = nb;
  }

  #pragma unroll
  for (int n=0;n<2;n++){
    int cn = col0 + wn*32 + n*16 + l16;
    #pragma unroll
    for (int m=0;m<4;m++)
      #pragma unroll
      for (int r=0;r<4;r++){
        int row = row0 + wm*64 + m*16 + lq*4 + r;
        tmp[(long)row*CH + cn] = f2b(acc[m][n][r]);
      }
  }
}

// ---------------- node stats pass1 ----------------
__global__ __launch_bounds__(512) void k_stats_node(
    int node, const unsigned short* __restrict__ tmp,
    const unsigned short* __restrict__ sb0, const unsigned short* __restrict__ sb1,
    const unsigned short* __restrict__ sb2, const unsigned short* __restrict__ sb3,
    const unsigned short* __restrict__ sb4,
    float* __restrict__ part, const int* __restrict__ idxp)
{
  int c = threadIdx.x;
  for (int jj = 0; jj < node; ++jj){
    int e = d_etab[node-1][jj];
    if (idxp[e] >= 2) continue;
    const unsigned short* S;
    switch(jj){ case 0: S=tmp; break; case 1: S=sb0; break; case 2: S=sb1; break;
                case 3: S=sb2; break; case 4: S=sb3; break; default: S=sb4; }
    const unsigned short* p = S + (long)blockIdx.x*128*CH + c;
    float s = 0.f, q = 0.f;
    for (int r = 0; r < 128; r++){ float v = b2f(p[(long)r*CH]); s += v; q += v*v; }
    long o = (((long)jj*128 + blockIdx.x)*CH + c)*2;
    part[o] = s; part[o+1] = q;
  }
}

// ---------------- node stats pass2 ----------------
__global__ __launch_bounds__(512) void k_stats2_node(
    int node, const float* __restrict__ part,
    float* __restrict__ alphaAll, float* __restrict__ mvalAll,
    const int* __restrict__ idxp)
{
  int c = threadIdx.x;
  for (int jj = 0; jj < node; ++jj){
    int e = d_etab[node-1][jj];
    int id = idxp[e];
    if (id >= 2) continue;
    float s = 0.f, q = 0.f;
    for (int b = 0; b < 128; b++){
      long o = (((long)jj*128 + b)*CH + c)*2;
      s += part[o]; q += part[o+1];
    }
    float m = s * (1.f/16384.f);
    float v = q * (1.f/16384.f) - m*m;
    v = fmaxf(v, 0.f);
    float al;
    if (jj == 0){
      float s1 = rsqrtf(v + EPSBN);
      float vz = v / (v + EPSBN);
      al = (id==0) ? (s1 * (1.f/9.f) * rsqrtf(vz*(1.f/81.f) + EPSBN))
                   : (s1 * rsqrtf(vz + EPSBN));
    } else {
      al = (id==0) ? ((1.f/9.f) * rsqrtf(v*(1.f/81.f) + EPSBN))
                   : rsqrtf(v + EPSBN);
    }
    alphaAll[(long)e*CH + c] = al;
    mvalAll[(long)e*CH + c] = m;
  }
}

// ---------------- fused per-node kernel ----------------
__global__ __launch_bounds__(256) void k_fused(
    int node,
    const unsigned short* __restrict__ xb,
    const unsigned short* __restrict__ sb0, const unsigned short* __restrict__ sb1,
    const unsigned short* __restrict__ sb2, const unsigned short* __restrict__ sb3,
    const unsigned short* __restrict__ sb4,
    unsigned short* __restrict__ sbout, float* __restrict__ outf,
    const unsigned short* __restrict__ tmp, const unsigned short* __restrict__ Wball,
    const float* __restrict__ dbA, const float* __restrict__ gbA,
    const float* __restrict__ dbB, const float* __restrict__ gbB,
    const float* __restrict__ alphaAll, const float* __restrict__ mvalAll,
    const int* __restrict__ idxp, const float* __restrict__ wscp)
{
  int bid = blockIdx.x;
  int lg = (bid & 7) * 128 + (bid >> 3);
  int rowTile = lg >> 3, colTile = lg & 7;
  int row0 = rowTile * 128, col0 = colTile * 64;

  int t = threadIdx.x;
  int lane = t & 63, wave = t >> 6;
  int wm = wave >> 1, wn = wave & 1;
  int l16 = lane & 15, lq = lane >> 4;

  __shared__ unsigned short LDS[12288];   // A0[4096] A1[4096] B0[2048] B1[2048]

  int ra = t >> 2;
  int ca = (((t & 3) ^ ((ra >> 1) & 3)) << 3);
  int aoff[4], boff[2];
  #pragma unroll
  for (int m=0;m<4;m++){ int R = wm*64 + m*16 + l16; aoff[m] = R*32 + ((lq ^ ((R>>1)&3))<<3); }
  #pragma unroll
  for (int n=0;n<2;n++){ int C = wn*32 + n*16 + l16; boff[n] = C*32 + ((lq ^ ((C>>1)&3))<<3); }

  f32x4 facc[4][2];
  #pragma unroll
  for (int m=0;m<4;m++){ facc[m][0]=(f32x4){0,0,0,0}; facc[m][1]=(f32x4){0,0,0,0}; }

  for (int jj = 0; jj < node; ++jj){
    int e = d_etab[node-1][jj];
    int id = idxp[e];
    if (id == 8) continue;
    float we = wscp[e];

    const unsigned short* st;
    switch(jj){ case 0: st=xb; break; case 1: st=sb0; break; case 2: st=sb1; break;
                case 3: st=sb2; break; case 4: st=sb3; break; default: st=sb4; }

    if (id < 2){
      // pool: facc += we*(S-m)*alpha
      const unsigned short* S = (jj==0) ? tmp : st;
      const float* al = alphaAll + (long)e*CH;
      const float* mv = mvalAll + (long)e*CH;
      #pragma unroll
      for (int n=0;n<2;n++){
        int cn = col0 + wn*32 + n*16 + l16;
        float a_n = al[cn], m_n = mv[cn];
        #pragma unroll
        for (int m=0;m<4;m++){
          int rowb = row0 + wm*64 + m*16 + lq*4;
          #pragma unroll
          for (int r=0;r<4;r++)
            facc[m][n][r] += we * (b2f(S[(long)(rowb+r)*CH + cn]) - m_n) * a_n;
        }
      }
      continue;
    }

    // GEMM edge (dense or group)
    bool grp = (id >= 5);
    int cin = (jj==0) ? 1024 : 512;
    int K = grp ? (cin >> 2) : cin;
    int act = grp ? id - 5 : id - 2;
    const unsigned short* Abase = st + (grp ? (long)(col0 >> 7)*K : 0);
    const unsigned short* Wbase = Wball + woff(e) + (long)col0*K;
    const float* bias;
    if (jj == 0) bias = (grp ? gbA : dbA) + ((long)e*3 + act)*CH;
    else         bias = (grp ? gbB : dbB) + ((long)d_bct[e]*3 + act)*CH;

    const unsigned short* gA0 = Abase + (long)(row0 + ra)*cin + ca;
    const unsigned short* gA1 = Abase + (long)(row0 + 64 + ra)*cin + ca;
    const unsigned short* gB  = Wbase + (long)ra*K + ca;

    f32x4 acc[4][2];
    #pragma unroll
    for (int m=0;m<4;m++){ acc[m][0]=(f32x4){0,0,0,0}; acc[m][1]=(f32x4){0,0,0,0}; }

    int nk = K >> 5;
    GLOAD16(gA0, &LDS[t*8]);
    GLOAD16(gA1, &LDS[2048 + t*8]);
    GLOAD16(gB,  &LDS[8192 + t*8]);
    __syncthreads();

    int buf = 0;
    for (int kt = 0; kt < nk; ++kt){
      int nb = buf ^ 1;
      if (kt+1 < nk){
        long kk = (long)(kt+1)*32;
        GLOAD16(gA0 + kk, &LDS[nb*4096 + t*8]);
        GLOAD16(gA1 + kk, &LDS[nb*4096 + 2048 + t*8]);
        GLOAD16(gB  + kk, &LDS[8192 + nb*2048 + t*8]);
      }
      const unsigned short* pA = &LDS[buf*4096];
      const unsigned short* pB = &LDS[8192 + buf*2048];
      short8 a[4], b[2];
      #pragma unroll
      for (int m=0;m<4;m++) a[m] = *(const short8*)(pA + aoff[m]);
      #pragma unroll
      for (int n=0;n<2;n++) b[n] = *(const short8*)(pB + boff[n]);
      #pragma unroll
      for (int m=0;m<4;m++)
        #pragma unroll
        for (int n=0;n<2;n++)
          acc[m][n] = __builtin_amdgcn_mfma_f32_16x16x32_bf16(a[m], b[n], acc[m][n], 0,0,0);
      __syncthreads();
      buf = nb;
    }

    #pragma unroll
    for (int n=0;n<2;n++){
      int cn = col0 + wn*32 + n*16 + l16;
      float bv = bias[cn];
      #pragma unroll
      for (int m=0;m<4;m++)
        #pragma unroll
        for (int r=0;r<4;r++){
          float v = acc[m][n][r] + bv;
          v = (act==0) ? fmaxf(v, 0.f) : (act==1) ? (1.f/(1.f+expf(-v))) : tanhf(v);
          facc[m][n][r] += we * v;
        }
    }
  }

  // epilogue: write state (bf16) or final output (fp32)
  #pragma unroll
  for (int n=0;n<2;n++){
    int cn = col0 + wn*32 + n*16 + l16;
    #pragma unroll
    for (int m=0;m<4;m++){
      int rowb = row0 + wm*64 + m*16 + lq*4;
      #pragma unroll
      for (int r=0;r<4;r++){
        long off = (long)(rowb+r)*CH + cn;
        if (node == 6) outf[off] = facc[m][n][r];
        else           sbout[off] = f2b(facc[m][n][r]);
      }
    }
  }
}

extern "C" void kernel_launch(void* const* d_in, const int* in_sizes, int n_in,
                              void* d_out, int out_size, void* d_ws, size_t ws_size,
                              hipStream_t stream)
{
  const float* x   = (const float*)d_in[0];
  const float* ap  = (const float*)d_in[1];
  const float* gum = (const float*)d_in[2];
  const float* dwA = (const float*)d_in[3];
  const float* dbA = (const float*)d_in[4];
  const float* gwA = (const float*)d_in[5];
  const float* gbA = (const float*)d_in[6];
  const float* pwA = (const float*)d_in[7];
  const float* dwB = (const float*)d_in[8];
  const float* dbB = (const float*)d_in[9];
  const float* gwB = (const float*)d_in[10];
  const float* gbB = (const float*)d_in[11];
  float* out = (float*)d_out;

  char* ws = (char*)d_ws;
  size_t cur = 0;
  auto alloc = [&](size_t bytes)->void*{
    size_t o = cur; cur += (bytes + 255) & ~(size_t)255; return (void*)(ws + o);
  };
  int*   idx      = (int*)  alloc(21*sizeof(int));
  float* wsc      = (float*)alloc(21*sizeof(float));
  float* alphaAll = (float*)alloc((size_t)21*CH*sizeof(float));
  float* mvalAll  = (float*)alloc((size_t)21*CH*sizeof(float));
  float* part     = (float*)alloc((size_t)6*128*CH*2*sizeof(float));
  unsigned short* Wball = (unsigned short*)alloc((size_t)7077888*sizeof(unsigned short));
  unsigned short* tmp   = (unsigned short*)alloc((size_t)BATCH*CH*sizeof(unsigned short));
  unsigned short* xb    = (unsigned short*)alloc((size_t)BATCH*1024*sizeof(unsigned short));
  unsigned short* sb[5];
  for (int i=0;i<5;i++)
    sb[i] = (unsigned short*)alloc((size_t)BATCH*CH*sizeof(unsigned short));

  if (cur > ws_size){
    hipLaunchKernelGGL(k_sentinel, dim3(1), dim3(1), 0, stream, out);
    return;
  }

  hipLaunchKernelGGL(k_f2b4, dim3(2048), dim3(256), 0, stream, x, xb, (long)BATCH*1024/4);
  hipLaunchKernelGGL(k_index, dim3(1), dim3(32), 0, stream, ap, gum, idx, wsc);
  hipLaunchKernelGGL(k_wconv_all, dim3(21*128), dim3(256), 0, stream,
                     idx, dwA, pwA, gwA, dwB, gwB, Wball);

  for (int node = 1; node <= 6; node++){
    hipLaunchKernelGGL(k_gemm_pool, dim3(1024), dim3(256), 0, stream,
                       node, xb, Wball, tmp, idx);
    hipLaunchKernelGGL(k_stats_node, dim3(128), dim3(512), 0, stream,
                       node, tmp, sb[0], sb[1], sb[2], sb[3], sb[4], part, idx);
    hipLaunchKernelGGL(k_stats2_node, dim3(1), dim3(512), 0, stream,
                       node, part, alphaAll, mvalAll, idx);
    hipLaunchKernelGGL(k_fused, dim3(1024), dim3(256), 0, stream,
                       node, xb, sb[0], sb[1], sb[2], sb[3], sb[4],
                       (node < 6) ? sb[node-1] : sb[0], out,
                       tmp, Wball, dbA, gbA, dbB, gbB,
                       alphaAll, mvalAll, idx, wsc);
  }
}